// Round 14
// baseline (885.078 us; speedup 1.0000x reference)
//
#include <hip/hip_runtime.h>
#include <hip/hip_bf16.h>

#define D 128
#define KTOP 3
#define NCLS 10
#define EPS 1e-5f
#define GBM 128   // rows per gemm block
#define BCAP 64   // fixed CSR bucket capacity per node

// ------- merged build: deg_out atomics ∥ cursor-scatter(idx) ∥ rowmax(x) ∥ score_init -------
// The two atomic streams (deg_out[src]++ and cursor[dst]++ + idx write) leave
// VALU ~98% idle and interleave on the fabric (measured R10/R12: merged ~230us
// vs 260 split). Scatter writes only the idx (.x of the int2 slot); weights are
// filled by wfill_pad once deg_out is complete.

__global__ __launch_bounds__(256) void build_kernel(
        const int* __restrict__ src, const int* __restrict__ dst,
        int* __restrict__ deg_out, int* __restrict__ cursor,
        int2* __restrict__ csrw, int E,
        const float* __restrict__ x, float* __restrict__ nodemax, int N,
        float* __restrict__ score, const float* __restrict__ pb0,
        const float* __restrict__ pb1, const float* __restrict__ pb2,
        const float* __restrict__ pb3, int G) {
    int b = blockIdx.x;
    int nbDeg = (E + 255) >> 8;
    if (b < nbDeg) {
        int e = b * 256 + threadIdx.x;
        if (e < E) atomicAdd(&deg_out[src[e]], 1);
        return;
    }
    b -= nbDeg;
    if (b < nbDeg) {
        int e = b * 256 + threadIdx.x;
        if (e < E) {
            int d = dst[e];
            int slot = atomicAdd(&cursor[d], 1);
            if (slot < BCAP)
                reinterpret_cast<int*>(csrw)[((size_t)d * BCAP + slot) * 2] = src[e];
        }
        return;
    }
    b -= nbDeg;
    int nbR = N >> 3;
    if (b < nbR) {
        int node = b * 8 + (threadIdx.x >> 5);
        int l = threadIdx.x & 31;
        float4 v = *reinterpret_cast<const float4*>(x + (size_t)node * D + 4 * l);
        float m = fmaxf(fmaxf(v.x, v.y), fmaxf(v.z, v.w));
#pragma unroll
        for (int d = 16; d > 0; d >>= 1) m = fmaxf(m, __shfl_xor(m, d, 64));
        if (l == 0) nodemax[node] = m;
        return;
    }
    for (int i = threadIdx.x; i < G * NCLS; i += 256) {
        int c = i % NCLS;
        score[i] = pb0[c] + pb1[c] + pb2[c] + pb3[c];
    }
}

// ---- weight fill + pad: touches ONLY slots < pad8(deg). Reads the idx, writes
// the FULL aligned int2 {idx, rsqrt(deg_out[idx])}; pad slots get {0,0}.
// deg_out (400 KB) is L2-hot. 4 nodes x 64 slots per block.

__global__ __launch_bounds__(256) void wfill_pad(const int* __restrict__ cursor,
        const int* __restrict__ deg_out, int2* __restrict__ csrw, int N) {
    int node = blockIdx.x * 4 + (threadIdx.x >> 6);
    int slot = threadIdx.x & 63;
    if (node >= N) return;
    int c = cursor[node]; if (c > BCAP) c = BCAP;
    int cpad = (c + 7) & ~7;
    if (slot >= cpad) return;
    int2* ent = csrw + (size_t)node * BCAP + slot;
    int2 out;
    if (slot < c) {
        int s = ent->x;
        int dg = deg_out[s]; if (dg < 1) dg = 1;
        out.x = s;
        out.y = __float_as_int(rsqrtf((float)dg));
    } else {
        out.x = 0; out.y = 0;
    }
    *ent = out;
}

__device__ __forceinline__ float4 bnrelu4(float4 v, float4 sc, float4 sh) {
    float4 r;
    r.x = fmaxf(fmaf(v.x, sc.x, sh.x), 0.f);
    r.y = fmaxf(fmaf(v.y, sc.y, sh.y), 0.f);
    r.z = fmaxf(fmaf(v.z, sc.z, sh.z), 0.f);
    r.w = fmaxf(fmaf(v.w, sc.w, sh.w), 0.f);
    return r;
}

// ---------------- fused aggregate (+on-the-fly BN/ReLU) + SortPool head ----------
// hin is the PRE-BN gemm output (or x when bns==nullptr). BN scale/shift derived
// from bnsums in LDS and applied per gathered element; the head applies the same
// transform to its 3 selected rows (selection via precomputed nodemax).

__global__ __launch_bounds__(256) void aggregate_head(
        const float* __restrict__ hin, const int* __restrict__ cursor,
        const int2* __restrict__ csrw, float* __restrict__ hout, int nAgg,
        const float* __restrict__ nodemax, const float* __restrict__ Pw,
        float* __restrict__ score, int NPG,
        const float* __restrict__ bns, const float* __restrict__ g,
        const float* __restrict__ bt, float invN) {
    __shared__ float ov[256];
    __shared__ float sv[256];
    __shared__ int   si[256];
    __shared__ int   sel[KTOP];
    __shared__ float sbuf[KTOP][D];
    __shared__ float red[4][NCLS];
    __shared__ float scs[D], shs[D];
    int b = blockIdx.x;
    int t = threadIdx.x;
    bool useBN = (bns != nullptr);
    if (useBN) {
        if (t < D) {
            float mu  = bns[t] * invN;
            float var = bns[D + t] * invN - mu * mu;
            float inv = rsqrtf(var + EPS);
            float s = g[t] * inv;
            scs[t] = s;
            shs[t] = bt[t] - mu * s;
        }
        __syncthreads();
    }
    if (b < nAgg) {
        int node = b * 8 + (t >> 5);
        int l = t & 31;
        int deg = cursor[node];
        int end = (deg + 7) & ~7; if (end > BCAP) end = BCAP;
        const int2* bkt = csrw + (size_t)node * BCAP;
        const float* base = hin + 4 * l;
        float4 sc4, sh4;
        if (useBN) {
            sc4 = *reinterpret_cast<const float4*>(&scs[4 * l]);
            sh4 = *reinterpret_cast<const float4*>(&shs[4 * l]);
        }
        float4 a0 = {0.f, 0.f, 0.f, 0.f}, a1 = a0;
        for (int e = 0; e < end; e += 8) {
            const int4* ce = reinterpret_cast<const int4*>(bkt + e);
            int4 p0 = ce[0], p1 = ce[1], p2 = ce[2], p3 = ce[3];
            float4 v0 = *reinterpret_cast<const float4*>(base + (size_t)p0.x * D);
            float4 v1 = *reinterpret_cast<const float4*>(base + (size_t)p0.z * D);
            float4 v2 = *reinterpret_cast<const float4*>(base + (size_t)p1.x * D);
            float4 v3 = *reinterpret_cast<const float4*>(base + (size_t)p1.z * D);
            float4 v4 = *reinterpret_cast<const float4*>(base + (size_t)p2.x * D);
            float4 v5 = *reinterpret_cast<const float4*>(base + (size_t)p2.z * D);
            float4 v6 = *reinterpret_cast<const float4*>(base + (size_t)p3.x * D);
            float4 v7 = *reinterpret_cast<const float4*>(base + (size_t)p3.z * D);
            if (useBN) {
                v0 = bnrelu4(v0, sc4, sh4); v1 = bnrelu4(v1, sc4, sh4);
                v2 = bnrelu4(v2, sc4, sh4); v3 = bnrelu4(v3, sc4, sh4);
                v4 = bnrelu4(v4, sc4, sh4); v5 = bnrelu4(v5, sc4, sh4);
                v6 = bnrelu4(v6, sc4, sh4); v7 = bnrelu4(v7, sc4, sh4);
            }
            float w0 = __int_as_float(p0.y), w1 = __int_as_float(p0.w);
            float w2 = __int_as_float(p1.y), w3 = __int_as_float(p1.w);
            float w4 = __int_as_float(p2.y), w5 = __int_as_float(p2.w);
            float w6 = __int_as_float(p3.y), w7 = __int_as_float(p3.w);
            a0.x += w0*v0.x; a0.y += w0*v0.y; a0.z += w0*v0.z; a0.w += w0*v0.w;
            a1.x += w1*v1.x; a1.y += w1*v1.y; a1.z += w1*v1.z; a1.w += w1*v1.w;
            a0.x += w2*v2.x; a0.y += w2*v2.y; a0.z += w2*v2.z; a0.w += w2*v2.w;
            a1.x += w3*v3.x; a1.y += w3*v3.y; a1.z += w3*v3.z; a1.w += w3*v3.w;
            a0.x += w4*v4.x; a0.y += w4*v4.y; a0.z += w4*v4.z; a0.w += w4*v4.w;
            a1.x += w5*v5.x; a1.y += w5*v5.y; a1.z += w5*v5.z; a1.w += w5*v5.w;
            a0.x += w6*v6.x; a0.y += w6*v6.y; a0.z += w6*v6.z; a0.w += w6*v6.w;
            a1.x += w7*v7.x; a1.y += w7*v7.y; a1.z += w7*v7.z; a1.w += w7*v7.w;
        }
        float ri = rsqrtf((float)(deg < 1 ? 1 : deg));
        float4 r;
        r.x = (a0.x + a1.x) * ri;
        r.y = (a0.y + a1.y) * ri;
        r.z = (a0.z + a1.z) * ri;
        r.w = (a0.w + a1.w) * ri;
        *reinterpret_cast<float4*>(hout + (size_t)node * D + 4 * l) = r;
        return;
    }

    // ---- SortPool head for this rep ----
    int gr = b - nAgg;
    ov[t] = (t < NPG) ? nodemax[(size_t)gr * NPG + t] : -3.4e38f;
    __syncthreads();
    for (int ks = 0; ks < KTOP; ++ks) {
        sv[t] = ov[t]; si[t] = t;
        __syncthreads();
        for (int s = 128; s > 0; s >>= 1) {
            if (t < s) {
                float a = sv[t], c = sv[t + s];
                int ia = si[t], ib = si[t + s];
                if (c > a || (c == a && ib < ia)) { sv[t] = c; si[t] = ib; }
            }
            __syncthreads();
        }
        if (t == 0) { sel[ks] = si[0]; ov[si[0]] = -3.4e38f; }
        __syncthreads();
    }
    int u = t >> 7, tl = t & 127;
    {
        float v = hin[((size_t)gr * NPG + sel[u]) * D + tl];
        sbuf[u][tl] = useBN ? fmaxf(fmaf(v, scs[tl], shs[tl]), 0.f) : v;
        if (t < 128) {
            float v2 = hin[((size_t)gr * NPG + sel[2]) * D + t];
            sbuf[2][t] = useBN ? fmaxf(fmaf(v2, scs[t], shs[t]), 0.f) : v2;
        }
    }
    __syncthreads();
    for (int size = 2; size <= D; size <<= 1) {
        for (int stride = size >> 1; stride > 0; stride >>= 1) {
            int ixj = tl ^ stride;
            if (ixj > tl) {
                float a = sbuf[u][tl], c = sbuf[u][ixj];
                bool up = ((tl & size) == 0);
                if ((a > c) == up) { sbuf[u][tl] = c; sbuf[u][ixj] = a; }
            }
            if (t < 128) {
                int ix2 = t ^ stride;
                if (ix2 > t) {
                    float a = sbuf[2][t], c = sbuf[2][ix2];
                    bool up = ((t & size) == 0);
                    if ((a > c) == up) { sbuf[2][t] = c; sbuf[2][ix2] = a; }
                }
            }
            __syncthreads();
        }
    }
    float part[NCLS];
    float v0 = sbuf[u][tl];
    const float* pw0 = Pw + (size_t)(u * D + tl) * NCLS;
#pragma unroll
    for (int c = 0; c < NCLS; ++c) part[c] = v0 * pw0[c];
    if (t < 128) {
        float v2 = sbuf[2][t];
        const float* pw2 = Pw + (size_t)(2 * D + t) * NCLS;
#pragma unroll
        for (int c = 0; c < NCLS; ++c) part[c] += v2 * pw2[c];
    }
    int lane = t & 63, wid = t >> 6;
#pragma unroll
    for (int c = 0; c < NCLS; ++c) {
        float xx = part[c];
#pragma unroll
        for (int o = 32; o > 0; o >>= 1) xx += __shfl_down(xx, o, 64);
        if (lane == 0) red[wid][c] = xx;
    }
    __syncthreads();
    if (t < NCLS)
        atomicAdd(&score[gr * NCLS + t],
                  red[0][t] + red[1][t] + red[2][t] + red[3][t]);
}

// ---------------- GEMM: W-in-LDS, A software-pipelined from global, fused bias+BN ----------------

__device__ __forceinline__ void gemm_chunk(const float* __restrict__ ain, size_t rowBase,
        int kc, int c0, const float (*Wl)[D], float (&acc)[4][8]) {
    const float* ap = ain + rowBase * D + kc;
    float4 a0 = *reinterpret_cast<const float4*>(ap);
    float4 a1 = *reinterpret_cast<const float4*>(ap + D);
    float4 a2 = *reinterpret_cast<const float4*>(ap + 2 * D);
    float4 a3 = *reinterpret_cast<const float4*>(ap + 3 * D);
#pragma unroll 2
    for (int k4 = 0; k4 < 16; ++k4) {
        float4 n0 = a0, n1 = a1, n2 = a2, n3 = a3;
        if (k4 < 15) {
            const float* np = ap + 4 * (k4 + 1);
            n0 = *reinterpret_cast<const float4*>(np);
            n1 = *reinterpret_cast<const float4*>(np + D);
            n2 = *reinterpret_cast<const float4*>(np + 2 * D);
            n3 = *reinterpret_cast<const float4*>(np + 3 * D);
        }
#pragma unroll
        for (int j = 0; j < 4; ++j) {
            int kk = 4 * k4 + j;
            float4 w0 = *reinterpret_cast<const float4*>(&Wl[kk][c0]);
            float4 w1 = *reinterpret_cast<const float4*>(&Wl[kk][c0 + 4]);
            float av[4];
            av[0] = (j==0)?a0.x:(j==1)?a0.y:(j==2)?a0.z:a0.w;
            av[1] = (j==0)?a1.x:(j==1)?a1.y:(j==2)?a1.z:a1.w;
            av[2] = (j==0)?a2.x:(j==1)?a2.y:(j==2)?a2.z:a2.w;
            av[3] = (j==0)?a3.x:(j==1)?a3.y:(j==2)?a3.z:a3.w;
            float wv[8] = {w0.x, w0.y, w0.z, w0.w, w1.x, w1.y, w1.z, w1.w};
#pragma unroll
            for (int i = 0; i < 4; ++i)
#pragma unroll
                for (int jj = 0; jj < 8; ++jj) acc[i][jj] += av[i] * wv[jj];
        }
        a0 = n0; a1 = n1; a2 = n2; a3 = n3;
    }
}

__global__ __launch_bounds__(512) void gemm_bn(const float* __restrict__ ain,
        const float* __restrict__ W, const float* __restrict__ bias,
        float* __restrict__ hout, float* __restrict__ bnsums, int N) {
    __shared__ __align__(16) float Wl[64][D];   // 32 KB
    int t = threadIdx.x;
    int cg = t & 15;
    int rs = t >> 4;
    int c0 = cg * 8;
    size_t rowBase = (size_t)blockIdx.x * GBM + 4 * rs;

    float acc[4][8];
#pragma unroll
    for (int i = 0; i < 4; ++i)
#pragma unroll
        for (int j = 0; j < 8; ++j) acc[i][j] = 0.f;

    const float4* Wv = reinterpret_cast<const float4*>(W);
    float4* Wd = reinterpret_cast<float4*>(&Wl[0][0]);
    float4 wpre[4];
#pragma unroll
    for (int i = 0; i < 4; ++i) wpre[i] = Wv[t + 512 * i];          // chunk 0
#pragma unroll
    for (int i = 0; i < 4; ++i) Wd[t + 512 * i] = wpre[i];
#pragma unroll
    for (int i = 0; i < 4; ++i) wpre[i] = Wv[2048 + t + 512 * i];   // chunk 1 in flight
    __syncthreads();
    gemm_chunk(ain, rowBase, 0, c0, Wl, acc);
    __syncthreads();
#pragma unroll
    for (int i = 0; i < 4; ++i) Wd[t + 512 * i] = wpre[i];
    __syncthreads();
    gemm_chunk(ain, rowBase, 64, c0, Wl, acc);

    float4 b0 = *reinterpret_cast<const float4*>(&bias[c0]);
    float4 b1 = *reinterpret_cast<const float4*>(&bias[c0 + 4]);
    float bv[8] = {b0.x, b0.y, b0.z, b0.w, b1.x, b1.y, b1.z, b1.w};
    float cs[8], cq[8];
#pragma unroll
    for (int j = 0; j < 8; ++j) { cs[j] = 0.f; cq[j] = 0.f; }
#pragma unroll
    for (int i = 0; i < 4; ++i) {
#pragma unroll
        for (int j = 0; j < 8; ++j) {
            float v = acc[i][j] + bv[j];
            acc[i][j] = v;
            cs[j] += v;
            cq[j] += v * v;
        }
    }
#pragma unroll
    for (int i = 0; i < 4; ++i) {
        size_t row = rowBase + i;
        float4 o0, o1;
        o0.x = acc[i][0]; o0.y = acc[i][1]; o0.z = acc[i][2]; o0.w = acc[i][3];
        o1.x = acc[i][4]; o1.y = acc[i][5]; o1.z = acc[i][6]; o1.w = acc[i][7];
        *reinterpret_cast<float4*>(&hout[row * D + c0])     = o0;
        *reinterpret_cast<float4*>(&hout[row * D + c0 + 4]) = o1;
    }
#pragma unroll
    for (int j = 0; j < 8; ++j) {
        cs[j] += __shfl_xor(cs[j], 16, 64); cq[j] += __shfl_xor(cq[j], 16, 64);
        cs[j] += __shfl_xor(cs[j], 32, 64); cq[j] += __shfl_xor(cq[j], 32, 64);
    }
    __syncthreads();                     // Wl now reusable
    float* red = &Wl[0][0];              // 8 waves x 256 floats
    int wid = t >> 6, lane = t & 63;
    if (lane < 16) {
#pragma unroll
        for (int j = 0; j < 8; ++j) {
            red[wid * 256 + lane * 16 + j]     = cs[j];
            red[wid * 256 + lane * 16 + 8 + j] = cq[j];
        }
    }
    __syncthreads();
    if (t < 256) {
        float s = 0.f;
#pragma unroll
        for (int w = 0; w < 8; ++w) s += red[w * 256 + t];
        int cgi = t >> 4, r = t & 15;
        int ch = cgi * 8 + (r & 7);
        atomicAdd(&bnsums[(r < 8 ? 0 : D) + ch], s);
    }
}

// ------- BN nodemax: per-node max of relu(h*sc+sh), NO write-back of h -------

__global__ __launch_bounds__(256) void bn_nodemax(const float* __restrict__ h,
        const float* __restrict__ bnsums, const float* __restrict__ g,
        const float* __restrict__ bt, float* __restrict__ nodemax, int N, float invN) {
    __shared__ float sc[D], sh[D];
    int t = threadIdx.x;
    if (t < D) {
        float mu  = bnsums[t] * invN;
        float var = bnsums[D + t] * invN - mu * mu;
        float inv = rsqrtf(var + EPS);
        float s = g[t] * inv;
        sc[t] = s;
        sh[t] = bt[t] - mu * s;
    }
    __syncthreads();
    int node = (blockIdx.x * 256 + t) >> 5;
    int l = t & 31;
    if (node >= N) return;
    float4 v = *reinterpret_cast<const float4*>(h + (size_t)node * D + 4 * l);
    float4 a = *reinterpret_cast<const float4*>(&sc[4 * l]);
    float4 b = *reinterpret_cast<const float4*>(&sh[4 * l]);
    v.x = fmaxf(fmaf(v.x, a.x, b.x), 0.f);
    v.y = fmaxf(fmaf(v.y, a.y, b.y), 0.f);
    v.z = fmaxf(fmaf(v.z, a.z, b.z), 0.f);
    v.w = fmaxf(fmaf(v.w, a.w, b.w), 0.f);
    float m = fmaxf(fmaxf(v.x, v.y), fmaxf(v.z, v.w));
#pragma unroll
    for (int d = 16; d > 0; d >>= 1) m = fmaxf(m, __shfl_xor(m, d, 64));
    if (l == 0) nodemax[node] = m;
}

// ---------------- launch ----------------

extern "C" void kernel_launch(void* const* d_in, const int* in_sizes, int n_in,
                              void* d_out, int out_size, void* d_ws, size_t ws_size,
                              hipStream_t stream) {
    const float* x   = (const float*)d_in[0];
    const int*   src = (const int*)d_in[1];
    const int*   dst = (const int*)d_in[2];
    const float* W[3]  = {(const float*)d_in[5],  (const float*)d_in[9],  (const float*)d_in[13]};
    const float* bb[3] = {(const float*)d_in[6],  (const float*)d_in[10], (const float*)d_in[14]};
    const float* gg[3] = {(const float*)d_in[7],  (const float*)d_in[11], (const float*)d_in[15]};
    const float* bt[3] = {(const float*)d_in[8],  (const float*)d_in[12], (const float*)d_in[16]};
    const float* Pw[4] = {(const float*)d_in[17], (const float*)d_in[19], (const float*)d_in[21], (const float*)d_in[23]};
    const float* Pb[4] = {(const float*)d_in[18], (const float*)d_in[20], (const float*)d_in[22], (const float*)d_in[24]};

    int N = in_sizes[0] / D;
    int E = in_sizes[1];
    int G = out_size / NCLS;
    int NPG = N / G;
    float* score = (float*)d_out;

    size_t NF = (size_t)N * D;
    float* fws     = (float*)d_ws;
    float* H       = fws;                  // NF (gemm out, pre-BN features)
    float* T       = H + NF;               // NF (aggregate out)
    float* nodemax = T + NF;               // N
    float* bnsums  = nodemax + N;          // 6*D
    int* deg_out = (int*)(bnsums + 6 * D); // N
    int* cursor  = deg_out + N;            // N
    int2* csrw   = (int2*)(cursor + N);    // N*BCAP (16B-aligned by layout)

    int nbDeg = (E + 255) >> 8;
    int nbR = N >> 3;
    float invN = 1.0f / (float)N;

    hipMemsetAsync(deg_out, 0, sizeof(int) * (size_t)2 * N, stream);  // deg_out + cursor
    hipMemsetAsync(bnsums, 0, sizeof(float) * 6 * D, stream);

    build_kernel<<<2 * nbDeg + nbR + 1, 256, 0, stream>>>(
        src, dst, deg_out, cursor, csrw, E, x, nodemax, N,
        score, Pb[0], Pb[1], Pb[2], Pb[3], G);
    wfill_pad<<<(N + 3) / 4, 256, 0, stream>>>(cursor, deg_out, csrw, N);

    int nAgg = N / 8;
    const float* hin = x;
    const float* curBns = nullptr;
    const float* curG = nullptr;
    const float* curBt = nullptr;
    for (int l = 0; l < 3; ++l) {
        float* bns = bnsums + l * 2 * D;
        // aggregate (BN_{l-1} folded) + head for rep l (feat=hin pre-BN)
        aggregate_head<<<nAgg + G, 256, 0, stream>>>(
            hin, cursor, csrw, T, nAgg, nodemax, Pw[l], score, NPG,
            curBns, curG, curBt, invN);
        gemm_bn<<<N / GBM, 512, 0, stream>>>(T, W[l], bb[l], H, bns, N);
        bn_nodemax<<<N / 8, 256, 0, stream>>>(H, bns, gg[l], bt[l], nodemax, N, invN);
        hin = H;
        curBns = bns; curG = gg[l]; curBt = bt[l];
    }
    // final head for rep 3 (nAgg=0 -> head-only grid, BN_2 applied to rows)
    aggregate_head<<<G, 256, 0, stream>>>(
        H, cursor, csrw, T, 0, nodemax, Pw[3], score, NPG,
        curBns, curG, curBt, invN);
}

// Round 15
// 798.272 us; speedup vs baseline: 1.1087x; 1.1087x over previous
//
#include <hip/hip_runtime.h>
#include <hip/hip_bf16.h>

#define D 128
#define KTOP 3
#define NCLS 10
#define EPS 1e-5f
#define GBM 128   // rows per gemm block
#define BCAP 64   // fixed CSR bucket capacity per node

// ------- prologue: XCD-sharded deg_out histogram + rowmax(x) + score_init -------
// Block b (xcd = b&7, chunk = b>>3) processes only edges with src in the xcd's
// node range. Round-robin block->XCD dispatch keeps each counter line in ONE
// XCD's L2 (no cross-XCD migration). Extra 8x edge reads ~= 51 MB, cheap.

__global__ __launch_bounds__(256) void prologue_kernel(
        const int* __restrict__ src,
        int* __restrict__ deg_out, int E,
        const float* __restrict__ x, float* __restrict__ nodemax, int N,
        float* __restrict__ score, const float* __restrict__ pb0,
        const float* __restrict__ pb1, const float* __restrict__ pb2,
        const float* __restrict__ pb3, int G) {
    int b = blockIdx.x;
    int nbDeg = (E + 255) >> 8;
    if (b < 8 * nbDeg) {
        int xcd = b & 7;
        int e = (b >> 3) * 256 + threadIdx.x;
        int lo = xcd * (N >> 3), hi = lo + (N >> 3);
        if (e < E) {
            int s = src[e];
            if (s >= lo && s < hi) atomicAdd(&deg_out[s], 1);
        }
        return;
    }
    b -= 8 * nbDeg;
    int nbR = N >> 3;
    if (b < nbR) {
        int node = b * 8 + (threadIdx.x >> 5);
        int l = threadIdx.x & 31;
        float4 v = *reinterpret_cast<const float4*>(x + (size_t)node * D + 4 * l);
        float m = fmaxf(fmaxf(v.x, v.y), fmaxf(v.z, v.w));
#pragma unroll
        for (int d = 16; d > 0; d >>= 1) m = fmaxf(m, __shfl_xor(m, d, 64));
        if (l == 0) nodemax[node] = m;
        return;
    }
    for (int i = threadIdx.x; i < G * NCLS; i += 256) {
        int c = i % NCLS;
        score[i] = pb0[c] + pb1[c] + pb2[c] + pb3[c];
    }
}

// ------- XCD-sharded scatter: block handles edges with dst in its xcd's range -------
// cursor atomics and csrw bucket lines for a node are all issued from one XCD.
// Writes {src, rsqrt(deg_out[src])}; deg_out (400 KB) is cache-hot.

__global__ __launch_bounds__(256) void csr_scatter(
        const int* __restrict__ src, const int* __restrict__ dst,
        const int* __restrict__ deg_out,
        int* __restrict__ cursor, int2* __restrict__ csrw, int E, int N) {
    int b = blockIdx.x;
    int xcd = b & 7;
    int e = (b >> 3) * 256 + threadIdx.x;
    if (e >= E) return;
    int d = dst[e];
    int lo = xcd * (N >> 3), hi = lo + (N >> 3);
    if (d < lo || d >= hi) return;
    int s = src[e];
    int slot = atomicAdd(&cursor[d], 1);
    if (slot >= BCAP) return;   // statistically unreachable (mean deg 16)
    int dg = deg_out[s]; if (dg < 1) dg = 1;
    int2 p; p.x = s; p.y = __float_as_int(rsqrtf((float)dg));
    csrw[(size_t)d * BCAP + slot] = p;
}

// zero-fill each bucket up to the next multiple of 8 (zero weights contribute 0)
__global__ void pad_kernel(const int* __restrict__ cursor, int2* __restrict__ csrw, int N) {
    int d = blockIdx.x * blockDim.x + threadIdx.x;
    if (d >= N) return;
    int c = cursor[d]; if (c > BCAP) c = BCAP;
    int end = (c + 7) & ~7;
    int2 z; z.x = 0; z.y = 0;
    for (int i = c; i < end; ++i) csrw[(size_t)d * BCAP + i] = z;
}

__device__ __forceinline__ float4 bnrelu4(float4 v, float4 sc, float4 sh) {
    float4 r;
    r.x = fmaxf(fmaf(v.x, sc.x, sh.x), 0.f);
    r.y = fmaxf(fmaf(v.y, sc.y, sh.y), 0.f);
    r.z = fmaxf(fmaf(v.z, sc.z, sh.z), 0.f);
    r.w = fmaxf(fmaf(v.w, sc.w, sh.w), 0.f);
    return r;
}

// ---------------- fused aggregate (+on-the-fly BN/ReLU) + SortPool head ----------
// hin is the PRE-BN gemm output (or x when bns==nullptr). BN scale/shift derived
// from bnsums in LDS and applied per gathered element; the head applies the same
// transform to its 3 selected rows (selection via precomputed nodemax).

__global__ __launch_bounds__(256) void aggregate_head(
        const float* __restrict__ hin, const int* __restrict__ cursor,
        const int2* __restrict__ csrw, float* __restrict__ hout, int nAgg,
        const float* __restrict__ nodemax, const float* __restrict__ Pw,
        float* __restrict__ score, int NPG,
        const float* __restrict__ bns, const float* __restrict__ g,
        const float* __restrict__ bt, float invN) {
    __shared__ float ov[256];
    __shared__ float sv[256];
    __shared__ int   si[256];
    __shared__ int   sel[KTOP];
    __shared__ float sbuf[KTOP][D];
    __shared__ float red[4][NCLS];
    __shared__ float scs[D], shs[D];
    int b = blockIdx.x;
    int t = threadIdx.x;
    bool useBN = (bns != nullptr);
    if (useBN) {
        if (t < D) {
            float mu  = bns[t] * invN;
            float var = bns[D + t] * invN - mu * mu;
            float inv = rsqrtf(var + EPS);
            float s = g[t] * inv;
            scs[t] = s;
            shs[t] = bt[t] - mu * s;
        }
        __syncthreads();
    }
    if (b < nAgg) {
        int node = b * 8 + (t >> 5);
        int l = t & 31;
        int deg = cursor[node];
        int end = (deg + 7) & ~7; if (end > BCAP) end = BCAP;
        const int2* bkt = csrw + (size_t)node * BCAP;
        const float* base = hin + 4 * l;
        float4 sc4, sh4;
        if (useBN) {
            sc4 = *reinterpret_cast<const float4*>(&scs[4 * l]);
            sh4 = *reinterpret_cast<const float4*>(&shs[4 * l]);
        }
        float4 a0 = {0.f, 0.f, 0.f, 0.f}, a1 = a0;
        for (int e = 0; e < end; e += 8) {
            const int4* ce = reinterpret_cast<const int4*>(bkt + e);
            int4 p0 = ce[0], p1 = ce[1], p2 = ce[2], p3 = ce[3];
            float4 v0 = *reinterpret_cast<const float4*>(base + (size_t)p0.x * D);
            float4 v1 = *reinterpret_cast<const float4*>(base + (size_t)p0.z * D);
            float4 v2 = *reinterpret_cast<const float4*>(base + (size_t)p1.x * D);
            float4 v3 = *reinterpret_cast<const float4*>(base + (size_t)p1.z * D);
            float4 v4 = *reinterpret_cast<const float4*>(base + (size_t)p2.x * D);
            float4 v5 = *reinterpret_cast<const float4*>(base + (size_t)p2.z * D);
            float4 v6 = *reinterpret_cast<const float4*>(base + (size_t)p3.x * D);
            float4 v7 = *reinterpret_cast<const float4*>(base + (size_t)p3.z * D);
            if (useBN) {
                v0 = bnrelu4(v0, sc4, sh4); v1 = bnrelu4(v1, sc4, sh4);
                v2 = bnrelu4(v2, sc4, sh4); v3 = bnrelu4(v3, sc4, sh4);
                v4 = bnrelu4(v4, sc4, sh4); v5 = bnrelu4(v5, sc4, sh4);
                v6 = bnrelu4(v6, sc4, sh4); v7 = bnrelu4(v7, sc4, sh4);
            }
            float w0 = __int_as_float(p0.y), w1 = __int_as_float(p0.w);
            float w2 = __int_as_float(p1.y), w3 = __int_as_float(p1.w);
            float w4 = __int_as_float(p2.y), w5 = __int_as_float(p2.w);
            float w6 = __int_as_float(p3.y), w7 = __int_as_float(p3.w);
            a0.x += w0*v0.x; a0.y += w0*v0.y; a0.z += w0*v0.z; a0.w += w0*v0.w;
            a1.x += w1*v1.x; a1.y += w1*v1.y; a1.z += w1*v1.z; a1.w += w1*v1.w;
            a0.x += w2*v2.x; a0.y += w2*v2.y; a0.z += w2*v2.z; a0.w += w2*v2.w;
            a1.x += w3*v3.x; a1.y += w3*v3.y; a1.z += w3*v3.z; a1.w += w3*v3.w;
            a0.x += w4*v4.x; a0.y += w4*v4.y; a0.z += w4*v4.z; a0.w += w4*v4.w;
            a1.x += w5*v5.x; a1.y += w5*v5.y; a1.z += w5*v5.z; a1.w += w5*v5.w;
            a0.x += w6*v6.x; a0.y += w6*v6.y; a0.z += w6*v6.z; a0.w += w6*v6.w;
            a1.x += w7*v7.x; a1.y += w7*v7.y; a1.z += w7*v7.z; a1.w += w7*v7.w;
        }
        float ri = rsqrtf((float)(deg < 1 ? 1 : deg));
        float4 r;
        r.x = (a0.x + a1.x) * ri;
        r.y = (a0.y + a1.y) * ri;
        r.z = (a0.z + a1.z) * ri;
        r.w = (a0.w + a1.w) * ri;
        *reinterpret_cast<float4*>(hout + (size_t)node * D + 4 * l) = r;
        return;
    }

    // ---- SortPool head for this rep ----
    int gr = b - nAgg;
    ov[t] = (t < NPG) ? nodemax[(size_t)gr * NPG + t] : -3.4e38f;
    __syncthreads();
    for (int ks = 0; ks < KTOP; ++ks) {
        sv[t] = ov[t]; si[t] = t;
        __syncthreads();
        for (int s = 128; s > 0; s >>= 1) {
            if (t < s) {
                float a = sv[t], c = sv[t + s];
                int ia = si[t], ib = si[t + s];
                if (c > a || (c == a && ib < ia)) { sv[t] = c; si[t] = ib; }
            }
            __syncthreads();
        }
        if (t == 0) { sel[ks] = si[0]; ov[si[0]] = -3.4e38f; }
        __syncthreads();
    }
    int u = t >> 7, tl = t & 127;
    {
        float v = hin[((size_t)gr * NPG + sel[u]) * D + tl];
        sbuf[u][tl] = useBN ? fmaxf(fmaf(v, scs[tl], shs[tl]), 0.f) : v;
        if (t < 128) {
            float v2 = hin[((size_t)gr * NPG + sel[2]) * D + t];
            sbuf[2][t] = useBN ? fmaxf(fmaf(v2, scs[t], shs[t]), 0.f) : v2;
        }
    }
    __syncthreads();
    for (int size = 2; size <= D; size <<= 1) {
        for (int stride = size >> 1; stride > 0; stride >>= 1) {
            int ixj = tl ^ stride;
            if (ixj > tl) {
                float a = sbuf[u][tl], c = sbuf[u][ixj];
                bool up = ((tl & size) == 0);
                if ((a > c) == up) { sbuf[u][tl] = c; sbuf[u][ixj] = a; }
            }
            if (t < 128) {
                int ix2 = t ^ stride;
                if (ix2 > t) {
                    float a = sbuf[2][t], c = sbuf[2][ix2];
                    bool up = ((t & size) == 0);
                    if ((a > c) == up) { sbuf[2][t] = c; sbuf[2][ix2] = a; }
                }
            }
            __syncthreads();
        }
    }
    float part[NCLS];
    float v0 = sbuf[u][tl];
    const float* pw0 = Pw + (size_t)(u * D + tl) * NCLS;
#pragma unroll
    for (int c = 0; c < NCLS; ++c) part[c] = v0 * pw0[c];
    if (t < 128) {
        float v2 = sbuf[2][t];
        const float* pw2 = Pw + (size_t)(2 * D + t) * NCLS;
#pragma unroll
        for (int c = 0; c < NCLS; ++c) part[c] += v2 * pw2[c];
    }
    int lane = t & 63, wid = t >> 6;
#pragma unroll
    for (int c = 0; c < NCLS; ++c) {
        float xx = part[c];
#pragma unroll
        for (int o = 32; o > 0; o >>= 1) xx += __shfl_down(xx, o, 64);
        if (lane == 0) red[wid][c] = xx;
    }
    __syncthreads();
    if (t < NCLS)
        atomicAdd(&score[gr * NCLS + t],
                  red[0][t] + red[1][t] + red[2][t] + red[3][t]);
}

// ---------------- GEMM: W-in-LDS, A software-pipelined from global, fused bias+BN ----------------

__device__ __forceinline__ void gemm_chunk(const float* __restrict__ ain, size_t rowBase,
        int kc, int c0, const float (*Wl)[D], float (&acc)[4][8]) {
    const float* ap = ain + rowBase * D + kc;
    float4 a0 = *reinterpret_cast<const float4*>(ap);
    float4 a1 = *reinterpret_cast<const float4*>(ap + D);
    float4 a2 = *reinterpret_cast<const float4*>(ap + 2 * D);
    float4 a3 = *reinterpret_cast<const float4*>(ap + 3 * D);
#pragma unroll 2
    for (int k4 = 0; k4 < 16; ++k4) {
        float4 n0 = a0, n1 = a1, n2 = a2, n3 = a3;
        if (k4 < 15) {
            const float* np = ap + 4 * (k4 + 1);
            n0 = *reinterpret_cast<const float4*>(np);
            n1 = *reinterpret_cast<const float4*>(np + D);
            n2 = *reinterpret_cast<const float4*>(np + 2 * D);
            n3 = *reinterpret_cast<const float4*>(np + 3 * D);
        }
#pragma unroll
        for (int j = 0; j < 4; ++j) {
            int kk = 4 * k4 + j;
            float4 w0 = *reinterpret_cast<const float4*>(&Wl[kk][c0]);
            float4 w1 = *reinterpret_cast<const float4*>(&Wl[kk][c0 + 4]);
            float av[4];
            av[0] = (j==0)?a0.x:(j==1)?a0.y:(j==2)?a0.z:a0.w;
            av[1] = (j==0)?a1.x:(j==1)?a1.y:(j==2)?a1.z:a1.w;
            av[2] = (j==0)?a2.x:(j==1)?a2.y:(j==2)?a2.z:a2.w;
            av[3] = (j==0)?a3.x:(j==1)?a3.y:(j==2)?a3.z:a3.w;
            float wv[8] = {w0.x, w0.y, w0.z, w0.w, w1.x, w1.y, w1.z, w1.w};
#pragma unroll
            for (int i = 0; i < 4; ++i)
#pragma unroll
                for (int jj = 0; jj < 8; ++jj) acc[i][jj] += av[i] * wv[jj];
        }
        a0 = n0; a1 = n1; a2 = n2; a3 = n3;
    }
}

__global__ __launch_bounds__(512) void gemm_bn(const float* __restrict__ ain,
        const float* __restrict__ W, const float* __restrict__ bias,
        float* __restrict__ hout, float* __restrict__ bnsums, int N) {
    __shared__ __align__(16) float Wl[64][D];   // 32 KB
    int t = threadIdx.x;
    int cg = t & 15;
    int rs = t >> 4;
    int c0 = cg * 8;
    size_t rowBase = (size_t)blockIdx.x * GBM + 4 * rs;

    float acc[4][8];
#pragma unroll
    for (int i = 0; i < 4; ++i)
#pragma unroll
        for (int j = 0; j < 8; ++j) acc[i][j] = 0.f;

    const float4* Wv = reinterpret_cast<const float4*>(W);
    float4* Wd = reinterpret_cast<float4*>(&Wl[0][0]);
    float4 wpre[4];
#pragma unroll
    for (int i = 0; i < 4; ++i) wpre[i] = Wv[t + 512 * i];          // chunk 0
#pragma unroll
    for (int i = 0; i < 4; ++i) Wd[t + 512 * i] = wpre[i];
#pragma unroll
    for (int i = 0; i < 4; ++i) wpre[i] = Wv[2048 + t + 512 * i];   // chunk 1 in flight
    __syncthreads();
    gemm_chunk(ain, rowBase, 0, c0, Wl, acc);
    __syncthreads();
#pragma unroll
    for (int i = 0; i < 4; ++i) Wd[t + 512 * i] = wpre[i];
    __syncthreads();
    gemm_chunk(ain, rowBase, 64, c0, Wl, acc);

    float4 b0 = *reinterpret_cast<const float4*>(&bias[c0]);
    float4 b1 = *reinterpret_cast<const float4*>(&bias[c0 + 4]);
    float bv[8] = {b0.x, b0.y, b0.z, b0.w, b1.x, b1.y, b1.z, b1.w};
    float cs[8], cq[8];
#pragma unroll
    for (int j = 0; j < 8; ++j) { cs[j] = 0.f; cq[j] = 0.f; }
#pragma unroll
    for (int i = 0; i < 4; ++i) {
#pragma unroll
        for (int j = 0; j < 8; ++j) {
            float v = acc[i][j] + bv[j];
            acc[i][j] = v;
            cs[j] += v;
            cq[j] += v * v;
        }
    }
#pragma unroll
    for (int i = 0; i < 4; ++i) {
        size_t row = rowBase + i;
        float4 o0, o1;
        o0.x = acc[i][0]; o0.y = acc[i][1]; o0.z = acc[i][2]; o0.w = acc[i][3];
        o1.x = acc[i][4]; o1.y = acc[i][5]; o1.z = acc[i][6]; o1.w = acc[i][7];
        *reinterpret_cast<float4*>(&hout[row * D + c0])     = o0;
        *reinterpret_cast<float4*>(&hout[row * D + c0 + 4]) = o1;
    }
#pragma unroll
    for (int j = 0; j < 8; ++j) {
        cs[j] += __shfl_xor(cs[j], 16, 64); cq[j] += __shfl_xor(cq[j], 16, 64);
        cs[j] += __shfl_xor(cs[j], 32, 64); cq[j] += __shfl_xor(cq[j], 32, 64);
    }
    __syncthreads();                     // Wl now reusable
    float* red = &Wl[0][0];              // 8 waves x 256 floats
    int wid = t >> 6, lane = t & 63;
    if (lane < 16) {
#pragma unroll
        for (int j = 0; j < 8; ++j) {
            red[wid * 256 + lane * 16 + j]     = cs[j];
            red[wid * 256 + lane * 16 + 8 + j] = cq[j];
        }
    }
    __syncthreads();
    if (t < 256) {
        float s = 0.f;
#pragma unroll
        for (int w = 0; w < 8; ++w) s += red[w * 256 + t];
        int cgi = t >> 4, r = t & 15;
        int ch = cgi * 8 + (r & 7);
        atomicAdd(&bnsums[(r < 8 ? 0 : D) + ch], s);
    }
}

// ------- BN nodemax: per-node max of relu(h*sc+sh), NO write-back of h -------

__global__ __launch_bounds__(256) void bn_nodemax(const float* __restrict__ h,
        const float* __restrict__ bnsums, const float* __restrict__ g,
        const float* __restrict__ bt, float* __restrict__ nodemax, int N, float invN) {
    __shared__ float sc[D], sh[D];
    int t = threadIdx.x;
    if (t < D) {
        float mu  = bnsums[t] * invN;
        float var = bnsums[D + t] * invN - mu * mu;
        float inv = rsqrtf(var + EPS);
        float s = g[t] * inv;
        sc[t] = s;
        sh[t] = bt[t] - mu * s;
    }
    __syncthreads();
    int node = (blockIdx.x * 256 + t) >> 5;
    int l = t & 31;
    if (node >= N) return;
    float4 v = *reinterpret_cast<const float4*>(h + (size_t)node * D + 4 * l);
    float4 a = *reinterpret_cast<const float4*>(&sc[4 * l]);
    float4 b = *reinterpret_cast<const float4*>(&sh[4 * l]);
    v.x = fmaxf(fmaf(v.x, a.x, b.x), 0.f);
    v.y = fmaxf(fmaf(v.y, a.y, b.y), 0.f);
    v.z = fmaxf(fmaf(v.z, a.z, b.z), 0.f);
    v.w = fmaxf(fmaf(v.w, a.w, b.w), 0.f);
    float m = fmaxf(fmaxf(v.x, v.y), fmaxf(v.z, v.w));
#pragma unroll
    for (int d = 16; d > 0; d >>= 1) m = fmaxf(m, __shfl_xor(m, d, 64));
    if (l == 0) nodemax[node] = m;
}

// ---------------- launch ----------------

extern "C" void kernel_launch(void* const* d_in, const int* in_sizes, int n_in,
                              void* d_out, int out_size, void* d_ws, size_t ws_size,
                              hipStream_t stream) {
    const float* x   = (const float*)d_in[0];
    const int*   src = (const int*)d_in[1];
    const int*   dst = (const int*)d_in[2];
    const float* W[3]  = {(const float*)d_in[5],  (const float*)d_in[9],  (const float*)d_in[13]};
    const float* bb[3] = {(const float*)d_in[6],  (const float*)d_in[10], (const float*)d_in[14]};
    const float* gg[3] = {(const float*)d_in[7],  (const float*)d_in[11], (const float*)d_in[15]};
    const float* bt[3] = {(const float*)d_in[8],  (const float*)d_in[12], (const float*)d_in[16]};
    const float* Pw[4] = {(const float*)d_in[17], (const float*)d_in[19], (const float*)d_in[21], (const float*)d_in[23]};
    const float* Pb[4] = {(const float*)d_in[18], (const float*)d_in[20], (const float*)d_in[22], (const float*)d_in[24]};

    int N = in_sizes[0] / D;
    int E = in_sizes[1];
    int G = out_size / NCLS;
    int NPG = N / G;
    float* score = (float*)d_out;

    size_t NF = (size_t)N * D;
    float* fws     = (float*)d_ws;
    float* H       = fws;                  // NF (gemm out, pre-BN features)
    float* T       = H + NF;               // NF (aggregate out)
    float* nodemax = T + NF;               // N
    float* bnsums  = nodemax + N;          // 6*D
    int* deg_out = (int*)(bnsums + 6 * D); // N
    int* cursor  = deg_out + N;            // N
    int2* csrw   = (int2*)(cursor + N);    // N*BCAP (16B-aligned by layout)

    int nbDeg = (E + 255) >> 8;
    int nbR = N >> 3;
    float invN = 1.0f / (float)N;

    hipMemsetAsync(deg_out, 0, sizeof(int) * (size_t)2 * N, stream);  // deg_out + cursor
    hipMemsetAsync(bnsums, 0, sizeof(float) * 6 * D, stream);

    prologue_kernel<<<8 * nbDeg + nbR + 1, 256, 0, stream>>>(
        src, deg_out, E, x, nodemax, N,
        score, Pb[0], Pb[1], Pb[2], Pb[3], G);
    csr_scatter<<<8 * nbDeg, 256, 0, stream>>>(src, dst, deg_out, cursor, csrw, E, N);
    pad_kernel<<<(N + 255) / 256, 256, 0, stream>>>(cursor, csrw, N);

    int nAgg = N / 8;
    const float* hin = x;
    const float* curBns = nullptr;
    const float* curG = nullptr;
    const float* curBt = nullptr;
    for (int l = 0; l < 3; ++l) {
        float* bns = bnsums + l * 2 * D;
        // aggregate (BN_{l-1} folded) + head for rep l (feat=hin pre-BN)
        aggregate_head<<<nAgg + G, 256, 0, stream>>>(
            hin, cursor, csrw, T, nAgg, nodemax, Pw[l], score, NPG,
            curBns, curG, curBt, invN);
        gemm_bn<<<N / GBM, 512, 0, stream>>>(T, W[l], bb[l], H, bns, N);
        bn_nodemax<<<N / 8, 256, 0, stream>>>(H, bns, gg[l], bt[l], nodemax, N, invN);
        hin = H;
        curBns = bns; curG = gg[l]; curBt = bt[l];
    }
    // final head for rep 3 (nAgg=0 -> head-only grid, BN_2 applied to rows)
    aggregate_head<<<G, 256, 0, stream>>>(
        H, cursor, csrw, T, 0, nodemax, Pw[3], score, NPG,
        curBns, curG, curBt, invN);
}